// Round 6
// baseline (97.764 us; speedup 1.0000x reference)
//
#include <hip/hip_runtime.h>
#include <math.h>

#define B_ 32
#define C_ 64
#define L_ 16384
#define LT 64                           // l-columns per tile
#define NT 4                            // pipelined tiles per block
#define NBLK (B_ * (L_ / (LT * NT)))    // 2048 blocks

typedef __attribute__((ext_vector_type(8))) short short8;
typedef __attribute__((ext_vector_type(4))) float f32x4;

__device__ __forceinline__ unsigned short f2bf(float x) {
  unsigned int u = __builtin_bit_cast(unsigned int, x);
  u += 0x7fffu + ((u >> 16) & 1u);   // RNE
  return (unsigned short)(u >> 16);
}

__device__ __forceinline__ float lrelu(float x) {
  return x >= 0.f ? x : 0.1f * x;
}

__device__ __forceinline__ void load_lds_16(const void* g, void* l) {
  __builtin_amdgcn_global_load_lds(
      (const __attribute__((address_space(1))) void*)g,
      (__attribute__((address_space(3))) void*)l, 16, 0, 0);
}
__device__ __forceinline__ void load_lds_4(const void* g, void* l) {
  __builtin_amdgcn_global_load_lds(
      (const __attribute__((address_space(1))) void*)g,
      (__attribute__((address_space(3))) void*)l, 4, 0, 0);
}

// ---------------------------------------------------------------------------
// Prep (tiny): kern4[b,c,4] = depthwise kernels (stride-4 padded);
// att[b,c] = sigmoid(lrelu(x1 ca1^T) ca2^T);
// wfrag = conv_w as bf16 MFMA A-fragments in per-lane load order.
// ---------------------------------------------------------------------------
__global__ void da_prep(const float* __restrict__ x1,
                        const float* __restrict__ W1,
                        const float* __restrict__ W2,
                        const float* __restrict__ ca_w1,
                        const float* __restrict__ ca_w2,
                        const float* __restrict__ conv_w,
                        float* __restrict__ kern4,
                        float* __restrict__ att,
                        unsigned short* __restrict__ wfrag) {
  int b = blockIdx.x;      // 32
  int t = threadIdx.x;     // 64
  __shared__ float x1s[64], h[64], a1[8];
  x1s[t] = x1[b * 64 + t];
  __syncthreads();
  {
    const float* w1r = W1 + t * 64;
    float s = 0.f;
    #pragma unroll
    for (int i = 0; i < 64; ++i) s = fmaf(x1s[i], w1r[i], s);
    h[t] = lrelu(s);
  }
  if (t < 8) {
    const float* cw = ca_w1 + t * 64;
    float a = 0.f;
    #pragma unroll
    for (int i = 0; i < 64; ++i) a = fmaf(x1s[i], cw[i], a);
    a1[t] = lrelu(a);
  }
  __syncthreads();
  #pragma unroll
  for (int kk = 0; kk < 3; ++kk) {
    const float* w2r = W2 + (t * 3 + kk) * 64;
    float s2 = 0.f;
    #pragma unroll
    for (int i = 0; i < 64; ++i) s2 = fmaf(h[i], w2r[i], s2);
    kern4[(b * 64 + t) * 4 + kk] = s2;
  }
  kern4[(b * 64 + t) * 4 + 3] = 0.f;
  {
    float a = 0.f;
    #pragma unroll
    for (int r = 0; r < 8; ++r) a = fmaf(a1[r], ca_w2[t * 8 + r], a);
    att[b * 64 + t] = 1.f / (1.f + expf(-a));
  }
  if (b == 0) {
    #pragma unroll
    for (int kt = 0; kt < 2; ++kt)
      #pragma unroll
      for (int mt = 0; mt < 4; ++mt)
        #pragma unroll
        for (int j = 0; j < 8; ++j) {
          float e = conv_w[(mt * 16 + (t & 15)) * 64 + kt * 32 + (t >> 4) * 8 + j];
          wfrag[(((kt * 4 + mt) * 64) + t) * 8 + j] = f2bf(e);
        }
  }
}

// ---------------------------------------------------------------------------
// Main: counted-vmcnt pipelined block (T3/T4). NT=4 tiles of LT=64 per block.
// ALL in-loop global reads are global_load_lds (no register results -> the
// compiler never inserts vmcnt waits; every wait below is hand-counted and
// never drains to 0 mid-loop; stores are never waited on).
// Per-wave vmem per iter: 4 stage glds (+1 halo glds, wave0) + 16 stores.
//   steady wait  = 16 stores + next stage(4|5)  -> vmcnt(20|21)
//   t=0          = next stage only              -> vmcnt(4|5)
//   t=NT-1       = 16 stores                    -> vmcnt(16)
// Halos: right-halo strip via 1 size-4 glds/tile (wave0, lane=row);
// left-halo carried wave3 -> LDS -> wave0 across the existing barriers.
// midT rows are wave-private (write AND read) -> no barrier for midT.
// x0s chunk swizzle + midT swizzle identical to r4 (verified conflict-free).
// ---------------------------------------------------------------------------
__global__ __launch_bounds__(256, 3) void da_main(
    const float* __restrict__ x0,
    const float* __restrict__ conv_b,
    const float* __restrict__ kern4,
    const float* __restrict__ att,
    const unsigned short* __restrict__ wfrag,
    float* __restrict__ out) {
  __shared__ float x0s[2][64 * LT];          // 2 x 16 KB
  __shared__ unsigned short midT[LT * 64];   // 8 KB
  __shared__ float haloL[2][64], haloR[2][64];

  int hw = blockIdx.x;
  int bid = (hw & 7) * (NBLK / 8) + (hw >> 3);   // XCD-contiguous swizzle
  int b = bid >> 6;                              // 64 windows per batch
  int base_l = (bid & 63) * (NT * LT);
  int tid = threadIdx.x;
  int lane = tid & 63;
  int wave = tid >> 6;

  int m_lane = lane & 15;
  int kbase = (lane >> 4) * 8;
  int qq = lane >> 4;

  const float* xb = x0 + (size_t)(b * 64) * L_;

  // ---- async stage of tile t1 into buffer d (4 glds/wave, 4 rows each)
  auto STAGE = [&](int t1, int d) {
    int p = lane & 15;
    int r4r = lane >> 4;
    #pragma unroll
    for (int i = 0; i < 4; ++i) {
      int c = wave * 16 + i * 4 + r4r;
      const float* g = xb + (size_t)c * L_ + base_l + t1 * LT + ((p ^ (c & 7)) << 2);
      load_lds_16(g, &x0s[d][(wave * 16 + i * 4) * LT]);
    }
  };
  // ---- right-halo of tile t1 (element l = base_l+(t1+1)*LT, all 64 rows)
  auto HALO = [&](int t1) {    // call from wave 0 only
    int l = base_l + (t1 + 1) * LT;
    if (l >= L_) l = base_l;   // clamp; Phase A substitutes 0 in that case
    const float* g = xb + (size_t)lane * L_ + l;
    load_lds_4(g, &haloR[t1 & 1][0]);
  };

  // ---- pre-loop register loads (all drained before first glds)
  short8 af[2][4];
  #pragma unroll
  for (int kt = 0; kt < 2; ++kt)
    #pragma unroll
    for (int mt = 0; mt < 4; ++mt)
      af[kt][mt] = *(const short8*)&wfrag[(((kt * 4 + mt) * 64) + lane) * 8];

  float4 kv = *(const float4*)&kern4[(b * 64 + lane) * 4];
  float k0 = kv.x, k1 = kv.y, k2 = kv.z;

  float cb_r[4][4], at_r[4][4];
  #pragma unroll
  for (int mt = 0; mt < 4; ++mt)
    #pragma unroll
    for (int r = 0; r < 4; ++r) {
      int o = mt * 16 + qq * 4 + r;
      cb_r[mt][r] = conv_b[o];
      at_r[mt][r] = att[b * 64 + o];
    }

  float hl0 = 0.f;
  if (wave == 0 && base_l > 0) hl0 = xb[(size_t)lane * L_ + base_l - 1];

  asm volatile("s_waitcnt vmcnt(0)" ::: "memory");   // drain ALL reg loads
  if (wave == 0) haloL[0][lane] = hl0;
  asm volatile("s_waitcnt lgkmcnt(0)" ::: "memory");

  // ---- prologue stage
  STAGE(0, 0);
  if (wave == 0) HALO(0);

  #pragma unroll
  for (int t = 0; t < NT; ++t) {
    const int d = t & 1;

    // issue next tile's loads first (deepest overlap)
    if (t + 1 < NT) {
      STAGE(t + 1, d ^ 1);
      if (wave == 0) HALO(t + 1);
    }

    // counted wait for THIS tile's stage+halo; stores stay in flight
    if (t == 0) {
      if (wave == 0) asm volatile("s_waitcnt vmcnt(5)" ::: "memory");
      else           asm volatile("s_waitcnt vmcnt(4)" ::: "memory");
    } else if (t < NT - 1) {
      if (wave == 0) asm volatile("s_waitcnt vmcnt(21)" ::: "memory");
      else           asm volatile("s_waitcnt vmcnt(20)" ::: "memory");
    } else {
      asm volatile("s_waitcnt vmcnt(16)" ::: "memory");
    }
    __builtin_amdgcn_s_barrier();          // bar1: staged tile visible

    // ---- Phase A: depthwise 3-tap + lrelu -> midT (wave-private rows)
    {
      int c = lane;
      int w0 = wave * 16;
      const float* row = &x0s[d][c * LT];
      const int csw = (c & 7) << 2;

      float4 q[4];
      #pragma unroll
      for (int i = 0; i < 4; ++i)
        q[i] = *(const float4*)&row[((wave * 4 + i) ^ (c & 7)) << 2];

      float prev, nxt;
      if (wave == 0) {
        prev = haloL[d][c];
      } else {
        int w = w0 - 1;
        prev = row[((w & ~3) ^ csw) + (w & 3)];
      }
      if (wave == 3) {
        bool oobR = (base_l + (t + 1) * LT) >= L_;
        nxt = oobR ? 0.f : haloR[d][c];
      } else {
        int w = w0 + 16;
        nxt = row[((w & ~3) ^ csw) + (w & 3)];
      }

      if (t + 1 < NT && wave == 3) haloL[d ^ 1][c] = q[3].w;  // left halo t+1

      #pragma unroll
      for (int i = 0; i < 4; ++i) {
        float xa = q[i].x, xb2 = q[i].y, xc = q[i].z, xd = q[i].w;
        float xm1 = prev;
        if (i > 0) xm1 = q[i - 1].w;
        float xp1 = nxt;
        if (i < 3) xp1 = q[i + 1].x;
        float m0 = fmaf(k0, xm1, fmaf(k1, xa,  k2 * xb2));
        float m1 = fmaf(k0, xa,  fmaf(k1, xb2, k2 * xc));
        float m2 = fmaf(k0, xb2, fmaf(k1, xc,  k2 * xd));
        float m3 = fmaf(k0, xc,  fmaf(k1, xd,  k2 * xp1));
        int l = w0 + 4 * i;
        midT[(l + 0) * 64 + (c ^ (((l + 0) & 7) << 3))] = f2bf(lrelu(m0));
        midT[(l + 1) * 64 + (c ^ (((l + 1) & 7) << 3))] = f2bf(lrelu(m1));
        midT[(l + 2) * 64 + (c ^ (((l + 2) & 7) << 3))] = f2bf(lrelu(m2));
        midT[(l + 3) * 64 + (c ^ (((l + 3) & 7) << 3))] = f2bf(lrelu(m3));
      }
    }
    // NO barrier: Phase B reads only midT rows this wave wrote (intra-wave
    // RAW handled by compiler lgkmcnt).

    // ---- Phase B: 1x1 conv via 16x16x32 bf16 MFMA
    f32x4 acc[4];
    #pragma unroll
    for (int mt = 0; mt < 4; ++mt) acc[mt] = (f32x4){0.f, 0.f, 0.f, 0.f};
    int l = wave * 16 + m_lane;
    #pragma unroll
    for (int kt = 0; kt < 2; ++kt) {
      int cb = kt * 32 + kbase;
      const short8 bf = *(const short8*)&midT[l * 64 + (cb ^ ((l & 7) << 3))];
      #pragma unroll
      for (int mt = 0; mt < 4; ++mt)
        acc[mt] = __builtin_amdgcn_mfma_f32_16x16x32_bf16(af[kt][mt], bf,
                                                          acc[mt], 0, 0, 0);
    }

    // ---- Epilogue: + conv_b + x0*att (x0 from LDS buf d), stores (no wait)
    {
      int w = wave * 16 + m_lane;
      int l0t = base_l + t * LT;
      #pragma unroll
      for (int mt = 0; mt < 4; ++mt) {
        #pragma unroll
        for (int r = 0; r < 4; ++r) {
          int o = mt * 16 + qq * 4 + r;
          float xv = x0s[d][o * LT + (((w & ~3) ^ ((o & 7) << 2)) + (w & 3))];
          out[(size_t)(b * 64 + o) * L_ + l0t + w] =
              acc[mt][r] + cb_r[mt][r] + xv * at_r[mt][r];
        }
      }
    }

    // bar2: all waves done reading buf d / halo strips before next overwrite
    if (t + 1 < NT) {
      asm volatile("s_waitcnt lgkmcnt(0)" ::: "memory");
      __builtin_amdgcn_s_barrier();
    }
  }
}

extern "C" void kernel_launch(void* const* d_in, const int* in_sizes, int n_in,
                              void* d_out, int out_size, void* d_ws, size_t ws_size,
                              hipStream_t stream) {
  const float* x0     = (const float*)d_in[0];
  const float* x1     = (const float*)d_in[1];
  const float* W1     = (const float*)d_in[2];
  const float* W2     = (const float*)d_in[3];
  const float* conv_w = (const float*)d_in[4];
  const float* conv_b = (const float*)d_in[5];
  const float* ca_w1  = (const float*)d_in[6];
  const float* ca_w2  = (const float*)d_in[7];
  float* out = (float*)d_out;

  float* kern4 = (float*)d_ws;                      // 32*64*4 = 8192 f
  float* att   = kern4 + B_ * C_ * 4;               // 2048 f
  unsigned short* wfrag = (unsigned short*)(att + B_ * C_);  // 4096 bf16

  da_prep<<<dim3(B_), dim3(64), 0, stream>>>(x1, W1, W2, ca_w1, ca_w2, conv_w,
                                             kern4, att, wfrag);
  da_main<<<dim3(NBLK), dim3(256), 0, stream>>>(x0, conv_b, kern4, att, wfrag,
                                                out);
}

// Round 7
// 64.984 us; speedup vs baseline: 1.5044x; 1.5044x over previous
//
#include <hip/hip_runtime.h>
#include <math.h>

#define B_ 32
#define C_ 64
#define L_ 16384
#define LT 64                           // l-columns per tile
#define NT 8                            // pipelined tiles per block
#define NBUF 3                          // staging buffers (depth-2 prefetch)
#define NBLK (B_ * (L_ / (LT * NT)))    // 1024 blocks

typedef __attribute__((ext_vector_type(8))) short short8;
typedef __attribute__((ext_vector_type(4))) float f32x4;

__device__ __forceinline__ unsigned short f2bf(float x) {
  unsigned int u = __builtin_bit_cast(unsigned int, x);
  u += 0x7fffu + ((u >> 16) & 1u);   // RNE
  return (unsigned short)(u >> 16);
}

__device__ __forceinline__ float lrelu(float x) {
  return x >= 0.f ? x : 0.1f * x;
}

__device__ __forceinline__ void load_lds_16(const void* g, void* l) {
  __builtin_amdgcn_global_load_lds(
      (const __attribute__((address_space(1))) void*)g,
      (__attribute__((address_space(3))) void*)l, 16, 0, 0);
}

// ---------------------------------------------------------------------------
// Prep (tiny): kern4[b,c,4] = depthwise kernels (stride-4 padded);
// att[b,c] = sigmoid(lrelu(x1 ca1^T) ca2^T);
// wfrag = conv_w as bf16 MFMA A-fragments in per-lane load order.
// ---------------------------------------------------------------------------
__global__ void da_prep(const float* __restrict__ x1,
                        const float* __restrict__ W1,
                        const float* __restrict__ W2,
                        const float* __restrict__ ca_w1,
                        const float* __restrict__ ca_w2,
                        const float* __restrict__ conv_w,
                        float* __restrict__ kern4,
                        float* __restrict__ att,
                        unsigned short* __restrict__ wfrag) {
  int b = blockIdx.x;      // 32
  int t = threadIdx.x;     // 64
  __shared__ float x1s[64], h[64], a1[8];
  x1s[t] = x1[b * 64 + t];
  __syncthreads();
  {
    const float* w1r = W1 + t * 64;
    float s = 0.f;
    #pragma unroll
    for (int i = 0; i < 64; ++i) s = fmaf(x1s[i], w1r[i], s);
    h[t] = lrelu(s);
  }
  if (t < 8) {
    const float* cw = ca_w1 + t * 64;
    float a = 0.f;
    #pragma unroll
    for (int i = 0; i < 64; ++i) a = fmaf(x1s[i], cw[i], a);
    a1[t] = lrelu(a);
  }
  __syncthreads();
  #pragma unroll
  for (int kk = 0; kk < 3; ++kk) {
    const float* w2r = W2 + (t * 3 + kk) * 64;
    float s2 = 0.f;
    #pragma unroll
    for (int i = 0; i < 64; ++i) s2 = fmaf(h[i], w2r[i], s2);
    kern4[(b * 64 + t) * 4 + kk] = s2;
  }
  kern4[(b * 64 + t) * 4 + 3] = 0.f;
  {
    float a = 0.f;
    #pragma unroll
    for (int r = 0; r < 8; ++r) a = fmaf(a1[r], ca_w2[t * 8 + r], a);
    att[b * 64 + t] = 1.f / (1.f + expf(-a));
  }
  if (b == 0) {
    #pragma unroll
    for (int kt = 0; kt < 2; ++kt)
      #pragma unroll
      for (int mt = 0; mt < 4; ++mt)
        #pragma unroll
        for (int j = 0; j < 8; ++j) {
          float e = conv_w[(mt * 16 + (t & 15)) * 64 + kt * 32 + (t >> 4) * 8 + j];
          wfrag[(((kt * 4 + mt) * 64) + t) * 8 + j] = f2bf(e);
        }
  }
}

// ---------------------------------------------------------------------------
// Main: depth-2 counted-vmcnt pipeline (T3/T4, m218-style). NT=8 tiles of
// LT=64 per block, 3 staging buffers (buf = t % 3).
// In-loop per-wave vmem = 4 stage glds + 16 stores, IDENTICAL on all waves;
// no in-loop register loads -> no compiler-inserted vmcnt.
// Wait covers tiles t AND t+1 (so t+1's buffer is readable for the right
// halo).  Steady wait: newer-than-stage(t+1) = stores(prev iter)(16) +
// stage(t+2)(4) = vmcnt(20); t=0: vmcnt(4); t=NT-2: vmcnt(16); t=NT-1: none.
// Stores never waited on mid-loop.
// Halos: right = word 0 of buf[(t+1)%3] (t<NT-1) else pre-loop reg->... reg;
//        left  = haloL strip (wave3 writes q[3].w for t+1), pre-loop reg t=0.
// midT rows are wave-private in write AND read -> no barrier for midT.
// Swizzles identical to r4 (verified conflict-free / 2-way max).
// ---------------------------------------------------------------------------
__global__ __launch_bounds__(256, 2) void da_main(
    const float* __restrict__ x0,
    const float* __restrict__ conv_b,
    const float* __restrict__ kern4,
    const float* __restrict__ att,
    const unsigned short* __restrict__ wfrag,
    float* __restrict__ out) {
  __shared__ float x0s[NBUF][64 * LT];       // 3 x 16 KB
  __shared__ unsigned short midT[LT * 64];   // 8 KB
  __shared__ float haloL[2][64];             // left-halo hand-off strips

  int bid = blockIdx.x;            // 0..1023
  int b = bid >> 5;                // 32 windows per batch
  int base_l = (bid & 31) * (NT * LT);
  int tid = threadIdx.x;
  int lane = tid & 63;
  int wave = tid >> 6;

  int m_lane = lane & 15;
  int kbase = (lane >> 4) * 8;
  int qq = lane >> 4;

  const float* xb = x0 + (size_t)(b * 64) * L_;

  // ---- async stage of tile t1 into buffer d (4 glds/wave, 4 rows each)
  auto STAGE = [&](int t1, int d) {
    int p = lane & 15;
    int r4r = lane >> 4;
    #pragma unroll
    for (int i = 0; i < 4; ++i) {
      int c = wave * 16 + i * 4 + r4r;
      const float* g = xb + (size_t)c * L_ + base_l + t1 * LT + ((p ^ (c & 7)) << 2);
      load_lds_16(g, &x0s[d][(wave * 16 + i * 4) * LT]);
    }
  };

  // ---- pre-loop register loads (drained before first glds)
  short8 af[2][4];
  #pragma unroll
  for (int kt = 0; kt < 2; ++kt)
    #pragma unroll
    for (int mt = 0; mt < 4; ++mt)
      af[kt][mt] = *(const short8*)&wfrag[(((kt * 4 + mt) * 64) + lane) * 8];

  float4 kv = *(const float4*)&kern4[(b * 64 + lane) * 4];
  float k0 = kv.x, k1 = kv.y, k2 = kv.z;

  float cb_r[4][4], at_r[4][4];
  #pragma unroll
  for (int mt = 0; mt < 4; ++mt)
    #pragma unroll
    for (int r = 0; r < 4; ++r) {
      int o = mt * 16 + qq * 4 + r;
      cb_r[mt][r] = conv_b[o];
      at_r[mt][r] = att[b * 64 + o];
    }

  // window-edge halos (register; wave0 = left edge, wave3 = right edge)
  float hl0 = 0.f, hnL = 0.f;
  if (wave == 0 && base_l > 0) hl0 = xb[(size_t)lane * L_ + base_l - 1];
  if (wave == 3 && base_l + NT * LT < L_)
    hnL = xb[(size_t)lane * L_ + base_l + NT * LT];

  if (wave == 0) haloL[0][lane] = hl0;
  __syncthreads();                 // drains vmcnt(0)+lgkmcnt(0) of all above

  // ---- prologue: stage tiles 0 and 1
  STAGE(0, 0);
  STAGE(1, 1);

  #pragma unroll
  for (int t = 0; t < NT; ++t) {
    const int d = t % NBUF;

    // issue tile t+2's stage (deepest overlap; buf (t+2)%3 is free: its
    // last readers finished before bar2(t-1))
    if (t + 2 < NT) STAGE(t + 2, (t + 2) % NBUF);

    // counted wait: tiles t and t+1 staged; stores stay in flight
    if (t == 0)
      asm volatile("s_waitcnt vmcnt(4)" ::: "memory");
    else if (t + 2 < NT)
      asm volatile("s_waitcnt vmcnt(20)" ::: "memory");
    else if (t + 2 == NT)
      asm volatile("s_waitcnt vmcnt(16)" ::: "memory");
    // t == NT-1: nothing new to wait for
    __builtin_amdgcn_s_barrier();          // bar1: tiles t, t+1 visible

    // ---- Phase A: depthwise 3-tap + lrelu -> midT (wave-private rows)
    {
      int c = lane;
      int w0 = wave * 16;
      const float* row = &x0s[d][c * LT];
      const int csw = (c & 7) << 2;

      float4 q[4];
      #pragma unroll
      for (int i = 0; i < 4; ++i)
        q[i] = *(const float4*)&row[((wave * 4 + i) ^ (c & 7)) << 2];

      float prev, nxt;
      if (wave == 0) {
        prev = (t == 0) ? hl0 : haloL[t & 1][c];
      } else {
        int w = w0 - 1;
        prev = row[((w & ~3) ^ csw) + (w & 3)];
      }
      if (wave == 3) {
        // right halo = word 0 of tile t+1 (resident in buf (t+1)%3)
        nxt = (t == NT - 1) ? hnL
                            : x0s[(t + 1) % NBUF][c * LT + ((c & 7) << 2)];
      } else {
        int w = w0 + 16;
        nxt = row[((w & ~3) ^ csw) + (w & 3)];
      }

      if (t + 1 < NT && wave == 3) haloL[(t + 1) & 1][c] = q[3].w;

      #pragma unroll
      for (int i = 0; i < 4; ++i) {
        float xa = q[i].x, xb2 = q[i].y, xc = q[i].z, xd = q[i].w;
        float xm1 = prev;
        if (i > 0) xm1 = q[i - 1].w;
        float xp1 = nxt;
        if (i < 3) xp1 = q[i + 1].x;
        float m0 = fmaf(k0, xm1, fmaf(k1, xa,  k2 * xb2));
        float m1 = fmaf(k0, xa,  fmaf(k1, xb2, k2 * xc));
        float m2 = fmaf(k0, xb2, fmaf(k1, xc,  k2 * xd));
        float m3 = fmaf(k0, xc,  fmaf(k1, xd,  k2 * xp1));
        int l = w0 + 4 * i;
        midT[(l + 0) * 64 + (c ^ (((l + 0) & 7) << 3))] = f2bf(lrelu(m0));
        midT[(l + 1) * 64 + (c ^ (((l + 1) & 7) << 3))] = f2bf(lrelu(m1));
        midT[(l + 2) * 64 + (c ^ (((l + 2) & 7) << 3))] = f2bf(lrelu(m2));
        midT[(l + 3) * 64 + (c ^ (((l + 3) & 7) << 3))] = f2bf(lrelu(m3));
      }
    }
    // NO barrier: Phase B reads only midT rows this wave wrote.

    // ---- Phase B: 1x1 conv via 16x16x32 bf16 MFMA
    f32x4 acc[4];
    #pragma unroll
    for (int mt = 0; mt < 4; ++mt) acc[mt] = (f32x4){0.f, 0.f, 0.f, 0.f};
    int l = wave * 16 + m_lane;
    #pragma unroll
    for (int kt = 0; kt < 2; ++kt) {
      int cb = kt * 32 + kbase;
      const short8 bf = *(const short8*)&midT[l * 64 + (cb ^ ((l & 7) << 3))];
      #pragma unroll
      for (int mt = 0; mt < 4; ++mt)
        acc[mt] = __builtin_amdgcn_mfma_f32_16x16x32_bf16(af[kt][mt], bf,
                                                          acc[mt], 0, 0, 0);
    }

    // ---- Epilogue: + conv_b + x0*att (x0 from LDS buf d), stores (no wait)
    {
      int w = wave * 16 + m_lane;
      int l0t = base_l + t * LT;
      #pragma unroll
      for (int mt = 0; mt < 4; ++mt) {
        #pragma unroll
        for (int r = 0; r < 4; ++r) {
          int o = mt * 16 + qq * 4 + r;
          float xv = x0s[d][o * LT + (((w & ~3) ^ ((o & 7) << 2)) + (w & 3))];
          out[(size_t)(b * 64 + o) * L_ + l0t + w] =
              acc[mt][r] + cb_r[mt][r] + xv * at_r[mt][r];
        }
      }
    }

    // bar2: all waves done reading buf d / haloL before next-iter overwrite
    if (t + 1 < NT) {
      asm volatile("s_waitcnt lgkmcnt(0)" ::: "memory");
      __builtin_amdgcn_s_barrier();
    }
  }
}

extern "C" void kernel_launch(void* const* d_in, const int* in_sizes, int n_in,
                              void* d_out, int out_size, void* d_ws, size_t ws_size,
                              hipStream_t stream) {
  const float* x0     = (const float*)d_in[0];
  const float* x1     = (const float*)d_in[1];
  const float* W1     = (const float*)d_in[2];
  const float* W2     = (const float*)d_in[3];
  const float* conv_w = (const float*)d_in[4];
  const float* conv_b = (const float*)d_in[5];
  const float* ca_w1  = (const float*)d_in[6];
  const float* ca_w2  = (const float*)d_in[7];
  float* out = (float*)d_out;

  float* kern4 = (float*)d_ws;                      // 32*64*4 = 8192 f
  float* att   = kern4 + B_ * C_ * 4;               // 2048 f
  unsigned short* wfrag = (unsigned short*)(att + B_ * C_);  // 4096 bf16

  da_prep<<<dim3(B_), dim3(64), 0, stream>>>(x1, W1, W2, ca_w1, ca_w2, conv_w,
                                             kern4, att, wfrag);
  da_main<<<dim3(NBLK), dim3(256), 0, stream>>>(x0, conv_b, kern4, att, wfrag,
                                                out);
}

// Round 8
// 63.804 us; speedup vs baseline: 1.5323x; 1.0185x over previous
//
#include <hip/hip_runtime.h>
#include <math.h>

#define B_ 32
#define C_ 64
#define L_ 16384
#define LT 32                           // l-columns per tile
#define NT 16                           // pipelined tiles per block
#define NBUF 3                          // staging buffers (depth-2 prefetch)
#define NBLK (B_ * (L_ / (LT * NT)))    // 1024 blocks -> 4/CU, all resident

typedef __attribute__((ext_vector_type(8))) short short8;
typedef __attribute__((ext_vector_type(4))) float f32x4;

__device__ __forceinline__ unsigned short f2bf(float x) {
  unsigned int u = __builtin_bit_cast(unsigned int, x);
  u += 0x7fffu + ((u >> 16) & 1u);   // RNE
  return (unsigned short)(u >> 16);
}

__device__ __forceinline__ float lrelu(float x) {
  return x >= 0.f ? x : 0.1f * x;
}

__device__ __forceinline__ void load_lds_16(const void* g, void* l) {
  __builtin_amdgcn_global_load_lds(
      (const __attribute__((address_space(1))) void*)g,
      (__attribute__((address_space(3))) void*)l, 16, 0, 0);
}

// ---------------------------------------------------------------------------
// Prep (tiny): kern4[b,c,4], att[b,c], wfrag = conv_w as bf16 A-frags in
// per-lane load order (unchanged from r4-r7).
// ---------------------------------------------------------------------------
__global__ void da_prep(const float* __restrict__ x1,
                        const float* __restrict__ W1,
                        const float* __restrict__ W2,
                        const float* __restrict__ ca_w1,
                        const float* __restrict__ ca_w2,
                        const float* __restrict__ conv_w,
                        float* __restrict__ kern4,
                        float* __restrict__ att,
                        unsigned short* __restrict__ wfrag) {
  int b = blockIdx.x;      // 32
  int t = threadIdx.x;     // 64
  __shared__ float x1s[64], h[64], a1[8];
  x1s[t] = x1[b * 64 + t];
  __syncthreads();
  {
    const float* w1r = W1 + t * 64;
    float s = 0.f;
    #pragma unroll
    for (int i = 0; i < 64; ++i) s = fmaf(x1s[i], w1r[i], s);
    h[t] = lrelu(s);
  }
  if (t < 8) {
    const float* cw = ca_w1 + t * 64;
    float a = 0.f;
    #pragma unroll
    for (int i = 0; i < 64; ++i) a = fmaf(x1s[i], cw[i], a);
    a1[t] = lrelu(a);
  }
  __syncthreads();
  #pragma unroll
  for (int kk = 0; kk < 3; ++kk) {
    const float* w2r = W2 + (t * 3 + kk) * 64;
    float s2 = 0.f;
    #pragma unroll
    for (int i = 0; i < 64; ++i) s2 = fmaf(h[i], w2r[i], s2);
    kern4[(b * 64 + t) * 4 + kk] = s2;
  }
  kern4[(b * 64 + t) * 4 + 3] = 0.f;
  {
    float a = 0.f;
    #pragma unroll
    for (int r = 0; r < 8; ++r) a = fmaf(a1[r], ca_w2[t * 8 + r], a);
    att[b * 64 + t] = 1.f / (1.f + expf(-a));
  }
  if (b == 0) {
    #pragma unroll
    for (int kt = 0; kt < 2; ++kt)
      #pragma unroll
      for (int mt = 0; mt < 4; ++mt)
        #pragma unroll
        for (int j = 0; j < 8; ++j) {
          float e = conv_w[(mt * 16 + (t & 15)) * 64 + kt * 32 + (t >> 4) * 8 + j];
          wfrag[(((kt * 4 + mt) * 64) + t) * 8 + j] = f2bf(e);
        }
  }
}

// ---------------------------------------------------------------------------
// Main: depth-2 counted-vmcnt pipeline, LT=32, NBUF=3, NT=16, 1024 blocks,
// 28.7 KB LDS -> 4 blocks/CU, ALL blocks resident (no generations).
// In-loop per-wave vmem = 2 stage glds + 8 stores (uniform, no reg loads);
// steady wait vmcnt(10) covers stage(t) AND stage(t+1); never 0 mid-loop.
// Phase split per iter:  [STAGE(t+2) | vmcnt | bar1 | PhaseA(->midT) +
// xv preread(buf d) | lgkm0 | bar_mid | PhaseB MFMA | stores]  (2 barriers).
// Wave w: PhaseA rows l=w*8..+8 (all 64 c); PhaseB o-half (w>>1), l-half (w&1).
// Right halo of tile t = word 0 of buf (t+1)%3 (staged, vmcnt-covered);
// left halo via haloL strip (wave3 -> wave0), window edges via registers.
// x0s: row c = 8 16B chunks, LDS slot p holds global chunk p^(c&7)
// (inverse-swizzled glds source, linear dest).  midT halfword idx =
// l*64 + (c^((l&7)<<3)).  Same verified-cheap patterns as r4/r7.
// ---------------------------------------------------------------------------
__global__ __launch_bounds__(256, 4) void da_main(
    const float* __restrict__ x0,
    const float* __restrict__ conv_b,
    const float* __restrict__ kern4,
    const float* __restrict__ att,
    const unsigned short* __restrict__ wfrag,
    float* __restrict__ out) {
  __shared__ float x0s[NBUF][64 * LT];       // 3 x 8 KB
  __shared__ unsigned short midT[LT * 64];   // 4 KB
  __shared__ float haloL[2][64];

  int bid = blockIdx.x;            // 0..1023
  int b = bid >> 5;                // 32 windows per batch
  int base_l = (bid & 31) * (NT * LT);       // window = 512 l
  int tid = threadIdx.x;
  int lane = tid & 63;
  int wave = tid >> 6;

  int m_lane = lane & 15;
  int qq = lane >> 4;
  int kbase = qq * 8;
  int oh = wave >> 1;              // o-half for Phase B
  int lh = wave & 1;               // l-half for Phase B
  int wl = lh * 16 + m_lane;       // this thread's l (Phase B / epilogue)

  const float* xb = x0 + (size_t)(b * 64) * L_;

  // ---- async stage of tile t1 into buffer dd (2 glds/wave, 8 rows each)
  auto STAGE = [&](int t1, int dd) {
    #pragma unroll
    for (int i = 0; i < 2; ++i) {
      int rg = (wave * 2 + i) * 8;           // row-group base
      int c = rg + (lane >> 3);
      int g = (lane & 7) ^ (c & 7);          // global chunk for LDS slot lane&7
      const float* gp = xb + (size_t)c * L_ + base_l + t1 * LT + g * 4;
      load_lds_16(gp, &x0s[dd][rg * LT]);
    }
  };

  // ---- pre-loop register loads (drained before first glds)
  short8 af[2][2];                 // A-frags: this wave's o-half only
  #pragma unroll
  for (int kt = 0; kt < 2; ++kt)
    #pragma unroll
    for (int mt2 = 0; mt2 < 2; ++mt2)
      af[kt][mt2] =
          *(const short8*)&wfrag[(((kt * 4 + oh * 2 + mt2) * 64) + lane) * 8];

  float4 kv = *(const float4*)&kern4[(b * 64 + lane) * 4];
  float k0 = kv.x, k1 = kv.y, k2 = kv.z;

  float cb_r[2][4], at_r[2][4];
  #pragma unroll
  for (int mt2 = 0; mt2 < 2; ++mt2)
    #pragma unroll
    for (int r = 0; r < 4; ++r) {
      int o = oh * 32 + mt2 * 16 + qq * 4 + r;
      cb_r[mt2][r] = conv_b[o];
      at_r[mt2][r] = att[b * 64 + o];
    }

  // window-edge halos
  float hl0 = 0.f, hnL = 0.f;
  if (wave == 0 && base_l > 0) hl0 = xb[(size_t)lane * L_ + base_l - 1];
  if (wave == 3 && base_l + NT * LT < L_)
    hnL = xb[(size_t)lane * L_ + base_l + NT * LT];
  if (wave == 0) haloL[0][lane] = hl0;

  __syncthreads();                 // drains vmcnt(0)+lgkmcnt(0) of all above

  // ---- prologue: stage tiles 0 and 1
  STAGE(0, 0);
  STAGE(1, 1);

  int cur = 0, nxt = 1, nx2 = 2;   // rotating buffer indices (t, t+1, t+2)
  for (int t = 0; t < NT; ++t) {
    // issue tile t+2 (deepest overlap); buf nx2 free since bar_mid(t-1)
    if (t + 2 < NT) STAGE(t + 2, nx2);

    // counted wait: stage(t) and stage(t+1) retired; stores left in flight
    if (t == 0)
      asm volatile("s_waitcnt vmcnt(2)" ::: "memory");
    else if (t < NT - 2)
      asm volatile("s_waitcnt vmcnt(10)" ::: "memory");
    else if (t == NT - 2)
      asm volatile("s_waitcnt vmcnt(8)" ::: "memory");
    // t == NT-1: stage(NT-1) already covered at t == NT-2
    __builtin_amdgcn_s_barrier();            // bar1: tiles t, t+1 visible

    // ---- Phase A: depthwise 3-tap + lrelu -> midT rows [wave*8, wave*8+8)
    {
      int c = lane;
      int cs = c & 7;
      const float* row = &x0s[cur][c * LT];

      float4 q0 = *(const float4*)&row[((wave * 2 + 0) ^ cs) << 2];
      float4 q1 = *(const float4*)&row[((wave * 2 + 1) ^ cs) << 2];

      float prev, nxtv;
      if (wave == 0) {
        prev = (t == 0) ? hl0 : haloL[t & 1][c];
      } else {
        prev = row[(((wave * 2 - 1) ^ cs) << 2) + 3];   // word w0-1
      }
      if (wave == 3) {
        nxtv = (t == NT - 1) ? hnL : x0s[nxt][c * LT + (cs << 2)];
      } else {
        nxtv = row[((wave * 2 + 2) ^ cs) << 2];          // word w0+8
      }
      if (wave == 3 && t + 1 < NT) haloL[(t + 1) & 1][c] = q1.w;

      float m0 = fmaf(k0, prev, fmaf(k1, q0.x, k2 * q0.y));
      float m1 = fmaf(k0, q0.x, fmaf(k1, q0.y, k2 * q0.z));
      float m2 = fmaf(k0, q0.y, fmaf(k1, q0.z, k2 * q0.w));
      float m3 = fmaf(k0, q0.z, fmaf(k1, q0.w, k2 * q1.x));
      float m4 = fmaf(k0, q0.w, fmaf(k1, q1.x, k2 * q1.y));
      float m5 = fmaf(k0, q1.x, fmaf(k1, q1.y, k2 * q1.z));
      float m6 = fmaf(k0, q1.y, fmaf(k1, q1.z, k2 * q1.w));
      float m7 = fmaf(k0, q1.z, fmaf(k1, q1.w, k2 * nxtv));

      int lb = wave * 8;                      // lb ≡ 0 mod 8 -> swz = j<<3
      midT[(lb + 0) * 64 + (c ^ (0 << 3))] = f2bf(lrelu(m0));
      midT[(lb + 1) * 64 + (c ^ (1 << 3))] = f2bf(lrelu(m1));
      midT[(lb + 2) * 64 + (c ^ (2 << 3))] = f2bf(lrelu(m2));
      midT[(lb + 3) * 64 + (c ^ (3 << 3))] = f2bf(lrelu(m3));
      midT[(lb + 4) * 64 + (c ^ (4 << 3))] = f2bf(lrelu(m4));
      midT[(lb + 5) * 64 + (c ^ (5 << 3))] = f2bf(lrelu(m5));
      midT[(lb + 6) * 64 + (c ^ (6 << 3))] = f2bf(lrelu(m6));
      midT[(lb + 7) * 64 + (c ^ (7 << 3))] = f2bf(lrelu(m7));
    }

    // ---- xv pre-read (residual x0 from buf cur) so buf recycles at bar_mid
    float xv[2][4];
    #pragma unroll
    for (int mt2 = 0; mt2 < 2; ++mt2)
      #pragma unroll
      for (int r = 0; r < 4; ++r) {
        int o = oh * 32 + mt2 * 16 + qq * 4 + r;
        xv[mt2][r] =
            x0s[cur][o * LT + (((wl >> 2) ^ (o & 7)) << 2) + (wl & 3)];
      }

    asm volatile("s_waitcnt lgkmcnt(0)" ::: "memory");
    __builtin_amdgcn_s_barrier();            // bar_mid: midT ready, bufs free

    // ---- Phase B: 1x1 conv via 16x16x32 bf16 MFMA (o-half oh, l-half lh)
    f32x4 acc[2];
    acc[0] = (f32x4){0.f, 0.f, 0.f, 0.f};
    acc[1] = (f32x4){0.f, 0.f, 0.f, 0.f};
    #pragma unroll
    for (int kt = 0; kt < 2; ++kt) {
      int cb = kt * 32 + kbase;
      const short8 bf =
          *(const short8*)&midT[wl * 64 + (cb ^ ((wl & 7) << 3))];
      acc[0] = __builtin_amdgcn_mfma_f32_16x16x32_bf16(af[kt][0], bf, acc[0],
                                                       0, 0, 0);
      acc[1] = __builtin_amdgcn_mfma_f32_16x16x32_bf16(af[kt][1], bf, acc[1],
                                                       0, 0, 0);
    }

    // ---- Epilogue: + conv_b + x0*att, stores (never waited on mid-loop)
    {
      size_t obase = (size_t)(b * 64) * L_ + base_l + t * LT + wl;
      #pragma unroll
      for (int mt2 = 0; mt2 < 2; ++mt2)
        #pragma unroll
        for (int r = 0; r < 4; ++r) {
          int o = oh * 32 + mt2 * 16 + qq * 4 + r;
          out[obase + (size_t)o * L_] =
              acc[mt2][r] + cb_r[mt2][r] + xv[mt2][r] * at_r[mt2][r];
        }
    }

    int tmp = cur; cur = nxt; nxt = nx2; nx2 = tmp;   // rotate buffers
  }
}

extern "C" void kernel_launch(void* const* d_in, const int* in_sizes, int n_in,
                              void* d_out, int out_size, void* d_ws, size_t ws_size,
                              hipStream_t stream) {
  const float* x0     = (const float*)d_in[0];
  const float* x1     = (const float*)d_in[1];
  const float* W1     = (const float*)d_in[2];
  const float* W2     = (const float*)d_in[3];
  const float* conv_w = (const float*)d_in[4];
  const float* conv_b = (const float*)d_in[5];
  const float* ca_w1  = (const float*)d_in[6];
  const float* ca_w2  = (const float*)d_in[7];
  float* out = (float*)d_out;

  float* kern4 = (float*)d_ws;                      // 32*64*4 = 8192 f
  float* att   = kern4 + B_ * C_ * 4;               // 2048 f
  unsigned short* wfrag = (unsigned short*)(att + B_ * C_);  // 4096 bf16

  da_prep<<<dim3(B_), dim3(64), 0, stream>>>(x1, W1, W2, ca_w1, ca_w2, conv_w,
                                             kern4, att, wfrag);
  da_main<<<dim3(NBLK), dim3(256), 0, stream>>>(x0, conv_b, kern4, att, wfrag,
                                                out);
}